// Round 1
// baseline (432.823 us; speedup 1.0000x reference)
//
#include <hip/hip_runtime.h>
#include <hip/hip_bf16.h>

// Problem: B=4, S=2048, E=1024, H=16, D=64.
// Pipeline (all bf16 MFMA with fp32 accum):
//   1. x fp32 -> xb bf16 [8192][1024]
//   2. w_qkv [1024][3072] -> wqkvT bf16 [3072][1024];  w_out -> woutT bf16 [1024][1024]
//   3. QKV GEMM -> Q [B,H,S,D] (pre-scaled 1/8), K [B,H,S,D], V^T [B,H,D,S]  (bf16)
//   4. flash attention -> attn bf16 [B,S,E]   (reuses xb region)
//   5. out GEMM (+bias) -> d_out fp32

typedef short bf16x8 __attribute__((ext_vector_type(8)));
typedef unsigned short u16x8 __attribute__((ext_vector_type(8)));
typedef float f32x4 __attribute__((ext_vector_type(4)));

__device__ inline short f2bf(float f) {
    unsigned int u = __builtin_bit_cast(unsigned int, f);
    u += 0x7fffu + ((u >> 16) & 1u);   // round-to-nearest-even
    return (short)(u >> 16);
}

__device__ inline float qmax16(float v) {
    v = fmaxf(v, __shfl_xor(v, 1));
    v = fmaxf(v, __shfl_xor(v, 2));
    v = fmaxf(v, __shfl_xor(v, 4));
    v = fmaxf(v, __shfl_xor(v, 8));
    return v;
}
__device__ inline float qsum16(float v) {
    v += __shfl_xor(v, 1);
    v += __shfl_xor(v, 2);
    v += __shfl_xor(v, 4);
    v += __shfl_xor(v, 8);
    return v;
}

// ---------------- conversion kernels ----------------

__global__ __launch_bounds__(256) void cvt_bf16_kernel(const float* __restrict__ in,
                                                       short* __restrict__ out) {
    int i = blockIdx.x * 256 + threadIdx.x;        // each thread: 8 elements
    const float4 a = *(const float4*)(in + (size_t)i * 8);
    const float4 b = *(const float4*)(in + (size_t)i * 8 + 4);
    u16x8 o;
    o[0] = (unsigned short)f2bf(a.x); o[1] = (unsigned short)f2bf(a.y);
    o[2] = (unsigned short)f2bf(a.z); o[3] = (unsigned short)f2bf(a.w);
    o[4] = (unsigned short)f2bf(b.x); o[5] = (unsigned short)f2bf(b.y);
    o[6] = (unsigned short)f2bf(b.z); o[7] = (unsigned short)f2bf(b.w);
    *(u16x8*)(out + (size_t)i * 8) = o;
}

// in [K][N] fp32  ->  out [N][K] bf16
__global__ __launch_bounds__(256) void transpose_cvt_kernel(const float* __restrict__ in,
                                                            short* __restrict__ out,
                                                            int K, int N) {
    __shared__ float tile[32][33];
    int tx = threadIdx.x & 31, ty = threadIdx.x >> 5;   // ty 0..7
    int nt = blockIdx.x * 32, kt = blockIdx.y * 32;
    for (int i = 0; i < 4; ++i)
        tile[ty + i * 8][tx] = in[(size_t)(kt + ty + i * 8) * N + nt + tx];
    __syncthreads();
    for (int i = 0; i < 4; ++i)
        out[(size_t)(nt + ty + i * 8) * K + kt + tx] = f2bf(tile[tx][ty + i * 8]);
}

// ---------------- QKV GEMM ----------------
// A = xb [8192][1024] bf16, Bt = wqkvT [3072][1024] bf16.  Tile 128x128, BK=32.
__global__ __launch_bounds__(256, 2) void gemm_qkv_kernel(
        const short* __restrict__ A, const short* __restrict__ Bt,
        const float* __restrict__ bias,
        short* __restrict__ Qg, short* __restrict__ Kg, short* __restrict__ Vtg) {
    __shared__ short As[128 * 40];
    __shared__ short Bs[128 * 40];
    const int t = threadIdx.x;
    const int w = t >> 6, lane = t & 63, r = lane & 15, q4 = lane >> 4;
    const int n0 = blockIdx.x * 128, m0 = blockIdx.y * 128;
    const int wm = (w & 1) * 64, wn = (w >> 1) * 64;
    const int sm = t >> 2;             // 0..63
    const int sk = (t & 3) * 8;        // 0,8,16,24

    f32x4 acc[4][4];
    for (int i = 0; i < 4; ++i)
        for (int j = 0; j < 4; ++j)
            acc[i][j] = (f32x4){0.f, 0.f, 0.f, 0.f};

    for (int kk = 0; kk < 1024; kk += 32) {
        *(u16x8*)(&As[sm * 40 + sk])        = *(const u16x8*)(A + (size_t)(m0 + sm) * 1024 + kk + sk);
        *(u16x8*)(&As[(sm + 64) * 40 + sk]) = *(const u16x8*)(A + (size_t)(m0 + sm + 64) * 1024 + kk + sk);
        *(u16x8*)(&Bs[sm * 40 + sk])        = *(const u16x8*)(Bt + (size_t)(n0 + sm) * 1024 + kk + sk);
        *(u16x8*)(&Bs[(sm + 64) * 40 + sk]) = *(const u16x8*)(Bt + (size_t)(n0 + sm + 64) * 1024 + kk + sk);
        __syncthreads();
        bf16x8 af[4], bfr[4];
        for (int i = 0; i < 4; ++i) af[i]  = *(const bf16x8*)(&As[(wm + i * 16 + r) * 40 + q4 * 8]);
        for (int j = 0; j < 4; ++j) bfr[j] = *(const bf16x8*)(&Bs[(wn + j * 16 + r) * 40 + q4 * 8]);
        for (int i = 0; i < 4; ++i)
            for (int j = 0; j < 4; ++j)
                acc[i][j] = __builtin_amdgcn_mfma_f32_16x16x32_bf16(af[i], bfr[j], acc[i][j], 0, 0, 0);
        __syncthreads();
    }

    // epilogue: scatter into Q (scaled), K, V^T
    for (int i = 0; i < 4; ++i) {
        for (int j = 0; j < 4; ++j) {
            const int gn = n0 + wn + j * 16 + r;
            const int h = gn / 192;
            const int rr = gn - h * 192;
            const float bv = bias[gn];
            for (int g = 0; g < 4; ++g) {
                const int gm = m0 + wm + i * 16 + q4 * 4 + g;
                const int bb = gm >> 11;          // batch
                const int s2 = gm & 2047;         // seq
                float v = acc[i][j][g] + bv;
                const size_t bh = (size_t)(bb * 16 + h);
                if (rr < 64) {
                    Qg[(bh * 2048 + s2) * 64 + rr] = f2bf(v * 0.125f);
                } else if (rr < 128) {
                    Kg[(bh * 2048 + s2) * 64 + (rr - 64)] = f2bf(v);
                } else {
                    Vtg[(bh * 64 + (rr - 128)) * 2048 + s2] = f2bf(v);
                }
            }
        }
    }
}

// ---------------- flash attention ----------------
// Q,K: [B,H,S,D] bf16 (Q pre-scaled), Vt: [B,H,D,S] bf16. Out: attn [B,S,H*D] bf16.
// Block: 256 thr = 4 waves; Bq=64 (16 q-rows/wave); Bk=64; 32 kv iters.
__global__ __launch_bounds__(256, 2) void attn_kernel(
        const short* __restrict__ Qg, const short* __restrict__ Kg,
        const short* __restrict__ Vtg, short* __restrict__ Og) {
    __shared__ short Ks[64 * 72];
    __shared__ short Vs[64 * 72];
    __shared__ short Ps[64 * 72];
    const int t = threadIdx.x;
    const int w = t >> 6, lane = t & 63, r = lane & 15, q4 = lane >> 4;
    const int blk = blockIdx.x;
    const int qt = blk & 31;
    const int h = (blk >> 5) & 15;
    const int b = blk >> 9;
    const size_t bh = (size_t)b * 16 + h;
    const short* Qb = Qg + bh * 2048 * 64;
    const short* Kb = Kg + bh * 2048 * 64;
    const short* Vb = Vtg + bh * 64 * 2048;

    const int qrow = qt * 64 + w * 16 + r;
    const bf16x8 qf0 = *(const bf16x8*)(Qb + (size_t)qrow * 64 + q4 * 8);
    const bf16x8 qf1 = *(const bf16x8*)(Qb + (size_t)qrow * 64 + 32 + q4 * 8);

    f32x4 o[4];
    for (int nt = 0; nt < 4; ++nt) o[nt] = (f32x4){0.f, 0.f, 0.f, 0.f};
    float m_i[4] = {-INFINITY, -INFINITY, -INFINITY, -INFINITY};
    float l_i[4] = {0.f, 0.f, 0.f, 0.f};

    for (int kt = 0; kt < 32; ++kt) {
        // stage K tile [64 keys][64 d] and Vt tile [64 d][64 keys], padded rows (72)
        for (int j2 = 0; j2 < 2; ++j2) {
            const int c = j2 * 256 + t;
            const int row = c >> 3;
            const int dc = (c & 7) * 8;
            *(u16x8*)(&Ks[row * 72 + dc]) = *(const u16x8*)(Kb + (size_t)kt * 4096 + row * 64 + dc);
            *(u16x8*)(&Vs[row * 72 + dc]) = *(const u16x8*)(Vb + (size_t)row * 2048 + kt * 64 + dc);
        }
        __syncthreads();

        // S = Q K^T  (4 col-tiles of 16 keys, two k-halves of d)
        f32x4 s[4];
        for (int c = 0; c < 4; ++c) {
            const bf16x8 kf0 = *(const bf16x8*)(&Ks[(c * 16 + r) * 72 + q4 * 8]);
            const bf16x8 kf1 = *(const bf16x8*)(&Ks[(c * 16 + r) * 72 + 32 + q4 * 8]);
            f32x4 z = (f32x4){0.f, 0.f, 0.f, 0.f};
            z = __builtin_amdgcn_mfma_f32_16x16x32_bf16(qf0, kf0, z, 0, 0, 0);
            z = __builtin_amdgcn_mfma_f32_16x16x32_bf16(qf1, kf1, z, 0, 0, 0);
            s[c] = z;
        }

        // online softmax (rows = q4*4+g, distributed over the 16 lanes of the quad)
        for (int g = 0; g < 4; ++g) {
            float v = fmaxf(fmaxf(s[0][g], s[1][g]), fmaxf(s[2][g], s[3][g]));
            v = qmax16(v);
            const float mnew = fmaxf(m_i[g], v);
            const float a = __expf(m_i[g] - mnew);
            float sum = 0.f;
            const int prow = (w * 16 + q4 * 4 + g) * 72;
            for (int c = 0; c < 4; ++c) {
                const float p = __expf(s[c][g] - mnew);
                sum += p;
                Ps[prow + c * 16 + r] = f2bf(p);
            }
            sum = qsum16(sum);
            l_i[g] = l_i[g] * a + sum;
            m_i[g] = mnew;
            for (int nt = 0; nt < 4; ++nt) o[nt][g] *= a;
        }
        asm volatile("s_waitcnt lgkmcnt(0)" ::: "memory");  // P writes visible (wave-local)

        // O += P V   (A = P from LDS, B = V^T rows contiguous in key)
        for (int ko = 0; ko < 2; ++ko) {
            const bf16x8 pf = *(const bf16x8*)(&Ps[(w * 16 + r) * 72 + ko * 32 + q4 * 8]);
            for (int nt = 0; nt < 4; ++nt) {
                const bf16x8 vf = *(const bf16x8*)(&Vs[(nt * 16 + r) * 72 + ko * 32 + q4 * 8]);
                o[nt] = __builtin_amdgcn_mfma_f32_16x16x32_bf16(pf, vf, o[nt], 0, 0, 0);
            }
        }
        __syncthreads();
    }

    // epilogue: divide by l, write attn [B,S,H*D]
    for (int g = 0; g < 4; ++g) {
        const float inv = 1.0f / l_i[g];
        const int srow = qt * 64 + w * 16 + q4 * 4 + g;
        const size_t rowoff = ((size_t)(b * 2048 + srow)) * 1024 + h * 64;
        for (int nt = 0; nt < 4; ++nt)
            Og[rowoff + nt * 16 + r] = f2bf(o[nt][g] * inv);
    }
}

// ---------------- output GEMM ----------------
// A = attn [8192][1024] bf16, Bt = woutT [1024][1024] bf16, out fp32 + bias.
__global__ __launch_bounds__(256, 2) void gemm_out_kernel(
        const short* __restrict__ A, const short* __restrict__ Bt,
        const float* __restrict__ bias, float* __restrict__ out) {
    __shared__ short As[128 * 40];
    __shared__ short Bs[128 * 40];
    const int t = threadIdx.x;
    const int w = t >> 6, lane = t & 63, r = lane & 15, q4 = lane >> 4;
    const int n0 = blockIdx.x * 128, m0 = blockIdx.y * 128;
    const int wm = (w & 1) * 64, wn = (w >> 1) * 64;
    const int sm = t >> 2;
    const int sk = (t & 3) * 8;

    f32x4 acc[4][4];
    for (int i = 0; i < 4; ++i)
        for (int j = 0; j < 4; ++j)
            acc[i][j] = (f32x4){0.f, 0.f, 0.f, 0.f};

    for (int kk = 0; kk < 1024; kk += 32) {
        *(u16x8*)(&As[sm * 40 + sk])        = *(const u16x8*)(A + (size_t)(m0 + sm) * 1024 + kk + sk);
        *(u16x8*)(&As[(sm + 64) * 40 + sk]) = *(const u16x8*)(A + (size_t)(m0 + sm + 64) * 1024 + kk + sk);
        *(u16x8*)(&Bs[sm * 40 + sk])        = *(const u16x8*)(Bt + (size_t)(n0 + sm) * 1024 + kk + sk);
        *(u16x8*)(&Bs[(sm + 64) * 40 + sk]) = *(const u16x8*)(Bt + (size_t)(n0 + sm + 64) * 1024 + kk + sk);
        __syncthreads();
        bf16x8 af[4], bfr[4];
        for (int i = 0; i < 4; ++i) af[i]  = *(const bf16x8*)(&As[(wm + i * 16 + r) * 40 + q4 * 8]);
        for (int j = 0; j < 4; ++j) bfr[j] = *(const bf16x8*)(&Bs[(wn + j * 16 + r) * 40 + q4 * 8]);
        for (int i = 0; i < 4; ++i)
            for (int j = 0; j < 4; ++j)
                acc[i][j] = __builtin_amdgcn_mfma_f32_16x16x32_bf16(af[i], bfr[j], acc[i][j], 0, 0, 0);
        __syncthreads();
    }

    for (int i = 0; i < 4; ++i) {
        for (int j = 0; j < 4; ++j) {
            const int gn = n0 + wn + j * 16 + r;
            const float bv = bias[gn];
            for (int g = 0; g < 4; ++g) {
                const int gm = m0 + wm + i * 16 + q4 * 4 + g;
                out[(size_t)gm * 1024 + gn] = acc[i][j][g] + bv;
            }
        }
    }
}

// ---------------- launch ----------------

extern "C" void kernel_launch(void* const* d_in, const int* in_sizes, int n_in,
                              void* d_out, int out_size, void* d_ws, size_t ws_size,
                              hipStream_t stream) {
    const float* x     = (const float*)d_in[0];
    const float* w_qkv = (const float*)d_in[1];
    const float* b_qkv = (const float*)d_in[2];
    const float* w_out = (const float*)d_in[3];
    const float* b_out = (const float*)d_in[4];
    float* out = (float*)d_out;

    char* ws = (char*)d_ws;
    short* xb    = (short*)(ws);                     // 16 MB, reused as attn output
    short* wqkvT = (short*)(ws + 16777216);          // 6 MB
    short* woutT = (short*)(ws + 23068672);          // 2 MB
    short* Qg    = (short*)(ws + 25165824);          // 16 MB
    short* Kg    = (short*)(ws + 41943040);          // 16 MB
    short* Vtg   = (short*)(ws + 58720256);          // 16 MB  (total 72 MB)
    short* attn  = xb;                               // alias: xb consumed before attn written

    cvt_bf16_kernel<<<4096, 256, 0, stream>>>(x, xb);                       // 8.4M elems
    transpose_cvt_kernel<<<dim3(96, 32), 256, 0, stream>>>(w_qkv, wqkvT, 1024, 3072);
    transpose_cvt_kernel<<<dim3(32, 32), 256, 0, stream>>>(w_out, woutT, 1024, 1024);
    gemm_qkv_kernel<<<dim3(24, 64), 256, 0, stream>>>(xb, wqkvT, b_qkv, Qg, Kg, Vtg);
    attn_kernel<<<2048, 256, 0, stream>>>(Qg, Kg, Vtg, attn);
    gemm_out_kernel<<<dim3(8, 64), 256, 0, stream>>>(attn, woutT, b_out, out);
}

// Round 2
// 388.771 us; speedup vs baseline: 1.1133x; 1.1133x over previous
//
#include <hip/hip_runtime.h>
#include <hip/hip_bf16.h>

// B=4, S=2048, E=1024, H=16, D=64.
// Pipeline (bf16 MFMA, fp32 accum):
//   1. x fp32 -> xb bf16 [8192][1024]
//   2. w_qkv -> wqkvT bf16 [3072][1024]; w_out -> woutT bf16 [1024][1024]
//   3. QKV GEMM (global_load_lds, BK=64, XOR swizzle) -> Q [B,H,S,D] (pre-scaled
//      by 0.125*log2e), K [B,H,S,D], V^T [B,H,D,S]
//   4. flash attention, S^T-swapped MFMA form -> attn bf16 [B,S,E]
//   5. out GEMM (+bias) -> d_out fp32

typedef short bf16x8 __attribute__((ext_vector_type(8)));
typedef unsigned short u16x8 __attribute__((ext_vector_type(8)));
typedef short s16x4 __attribute__((ext_vector_type(4)));
typedef float f32x4 __attribute__((ext_vector_type(4)));

#define QSCALE 0.18033688011112042f   // 0.125 * log2(e)

__device__ inline short f2bf(float f) {
    unsigned int u = __builtin_bit_cast(unsigned int, f);
    u += 0x7fffu + ((u >> 16) & 1u);   // round-to-nearest-even
    return (short)(u >> 16);
}

__device__ inline void gload_lds16(const short* g, short* l) {
    __builtin_amdgcn_global_load_lds(
        (const __attribute__((address_space(1))) unsigned int*)g,
        (__attribute__((address_space(3))) unsigned int*)l, 16, 0, 0);
}

// ---------------- conversion kernels ----------------

__global__ __launch_bounds__(256) void cvt_bf16_kernel(const float* __restrict__ in,
                                                       short* __restrict__ out) {
    int i = blockIdx.x * 256 + threadIdx.x;        // each thread: 8 elements
    const float4 a = *(const float4*)(in + (size_t)i * 8);
    const float4 b = *(const float4*)(in + (size_t)i * 8 + 4);
    u16x8 o;
    o[0] = (unsigned short)f2bf(a.x); o[1] = (unsigned short)f2bf(a.y);
    o[2] = (unsigned short)f2bf(a.z); o[3] = (unsigned short)f2bf(a.w);
    o[4] = (unsigned short)f2bf(b.x); o[5] = (unsigned short)f2bf(b.y);
    o[6] = (unsigned short)f2bf(b.z); o[7] = (unsigned short)f2bf(b.w);
    *(u16x8*)(out + (size_t)i * 8) = o;
}

// in [K][N] fp32  ->  out [N][K] bf16
__global__ __launch_bounds__(256) void transpose_cvt_kernel(const float* __restrict__ in,
                                                            short* __restrict__ out,
                                                            int K, int N) {
    __shared__ float tile[32][33];
    int tx = threadIdx.x & 31, ty = threadIdx.x >> 5;   // ty 0..7
    int nt = blockIdx.x * 32, kt = blockIdx.y * 32;
    for (int i = 0; i < 4; ++i)
        tile[ty + i * 8][tx] = in[(size_t)(kt + ty + i * 8) * N + nt + tx];
    __syncthreads();
    for (int i = 0; i < 4; ++i)
        out[(size_t)(nt + ty + i * 8) * K + kt + tx] = f2bf(tile[tx][ty + i * 8]);
}

// ---------------- QKV GEMM ----------------
// A = xb [8192][1024] bf16, Bt = wqkvT [3072][1024] bf16.  Tile 128x128, BK=64.
// LDS staged via global_load_lds (16B/lane), XOR granule swizzle:
//   LDS slot (row, gs) holds global granule gs ^ (row&7)   (granule = 8 shorts)
__global__ __launch_bounds__(256, 2) void gemm_qkv_kernel(
        const short* __restrict__ A, const short* __restrict__ Bt,
        const float* __restrict__ bias,
        short* __restrict__ Qg, short* __restrict__ Kg, short* __restrict__ Vtg) {
    __shared__ short As[128 * 64];
    __shared__ short Bs[128 * 64];
    const int t = threadIdx.x;
    const int w = t >> 6, lane = t & 63, r = lane & 15, q4 = lane >> 4;
    const int n0 = blockIdx.x * 128, m0 = blockIdx.y * 128;
    const int wm = (w & 1) * 64, wn = (w >> 1) * 64;

    f32x4 acc[4][4];
    for (int i = 0; i < 4; ++i)
        for (int j = 0; j < 4; ++j)
            acc[i][j] = (f32x4){0.f, 0.f, 0.f, 0.f};

    for (int kk = 0; kk < 1024; kk += 64) {
        for (int ii = 0; ii < 4; ++ii) {
            const int p = t + 256 * ii;
            const int row = p >> 3;
            const int gg = (p & 7) ^ (row & 7);
            gload_lds16(A + (size_t)(m0 + row) * 1024 + kk + gg * 8, &As[p * 8]);
            gload_lds16(Bt + (size_t)(n0 + row) * 1024 + kk + gg * 8, &Bs[p * 8]);
        }
        __syncthreads();
        for (int ko = 0; ko < 2; ++ko) {
            bf16x8 af[4], bfr[4];
            for (int i = 0; i < 4; ++i) {
                const int R = wm + i * 16 + r;
                af[i] = *(const bf16x8*)(&As[R * 64 + (((ko * 4 + q4) ^ (R & 7)) * 8)]);
            }
            for (int j = 0; j < 4; ++j) {
                const int R = wn + j * 16 + r;
                bfr[j] = *(const bf16x8*)(&Bs[R * 64 + (((ko * 4 + q4) ^ (R & 7)) * 8)]);
            }
            for (int i = 0; i < 4; ++i)
                for (int j = 0; j < 4; ++j)
                    acc[i][j] = __builtin_amdgcn_mfma_f32_16x16x32_bf16(af[i], bfr[j], acc[i][j], 0, 0, 0);
        }
        __syncthreads();
    }

    // epilogue: scatter into Q (scaled by 0.125*log2e), K, V^T
    for (int i = 0; i < 4; ++i) {
        for (int j = 0; j < 4; ++j) {
            const int gn = n0 + wn + j * 16 + r;
            const int h = gn / 192;
            const int rr = gn - h * 192;
            const float bv = bias[gn];
            for (int g = 0; g < 4; ++g) {
                const int gm = m0 + wm + i * 16 + q4 * 4 + g;
                const int bb = gm >> 11;          // batch
                const int s2 = gm & 2047;         // seq
                float v = acc[i][j][g] + bv;
                const size_t bh = (size_t)(bb * 16 + h);
                if (rr < 64) {
                    Qg[(bh * 2048 + s2) * 64 + rr] = f2bf(v * QSCALE);
                } else if (rr < 128) {
                    Kg[(bh * 2048 + s2) * 64 + (rr - 64)] = f2bf(v);
                } else {
                    Vtg[(bh * 64 + (rr - 128)) * 2048 + s2] = f2bf(v);
                }
            }
        }
    }
}

// ---------------- flash attention (S^T-swapped) ----------------
// Q,K: [B,H,S,D] bf16 (Q pre-scaled by 0.125*log2e), Vt: [B,H,D,S] bf16.
// Out: attn [B,S,H*D] bf16.
// Block: 256 thr = 4 waves; Bq=128 (2 q-subtiles of 16 per wave); Bk=64; 32 kv iters.
// S^T = K.Q^T  (A=K-frag, B=Q-frag)  -> lane holds S^T[key=c*16+q4*4+g][query=r]
// O^T = V^T.P^T (A=V^T-frag, B=P^T-frag from LDS row-major P[query][key])
__global__ __launch_bounds__(256, 2) void attn_kernel(
        const short* __restrict__ Qg, const short* __restrict__ Kg,
        const short* __restrict__ Vtg, short* __restrict__ Og) {
    __shared__ short Ks[64 * 72];
    __shared__ short Vs[64 * 72];
    __shared__ short Ps[128 * 72];    // per wave: 2 q-subtiles x 16 rows x 72
    const int t = threadIdx.x;
    const int w = t >> 6, lane = t & 63, r = lane & 15, q4 = lane >> 4;
    const int blk = blockIdx.x;
    const int qt = blk & 15;
    const int h = (blk >> 4) & 15;
    const int b = blk >> 8;
    const size_t bh = (size_t)b * 16 + h;
    const short* Qb = Qg + bh * 2048 * 64;
    const short* Kb = Kg + bh * 2048 * 64;
    const short* Vb = Vtg + bh * 64 * 2048;

    // Q fragments (B-operand): lane holds Q[qrow=...+r][d = ko*32 + q4*8 ..]
    bf16x8 qf[2][2];
    for (int qs = 0; qs < 2; ++qs) {
        const int qrow = qt * 128 + w * 32 + qs * 16 + r;
        qf[qs][0] = *(const bf16x8*)(Qb + (size_t)qrow * 64 + q4 * 8);
        qf[qs][1] = *(const bf16x8*)(Qb + (size_t)qrow * 64 + 32 + q4 * 8);
    }

    f32x4 o[2][4];
    for (int qs = 0; qs < 2; ++qs)
        for (int nt = 0; nt < 4; ++nt) o[qs][nt] = (f32x4){0.f, 0.f, 0.f, 0.f};
    float m_i[2] = {-INFINITY, -INFINITY};
    float l_i[2] = {0.f, 0.f};

    const int pbase0 = (w * 32) * 72;

    for (int kt = 0; kt < 32; ++kt) {
        // stage K tile [64 keys][64 d] and Vt tile [64 d][64 keys], stride 72
        for (int j2 = 0; j2 < 2; ++j2) {
            const int c = j2 * 256 + t;
            const int row = c >> 3;
            const int dc = (c & 7) * 8;
            *(u16x8*)(&Ks[row * 72 + dc]) = *(const u16x8*)(Kb + (size_t)kt * 4096 + row * 64 + dc);
            *(u16x8*)(&Vs[row * 72 + dc]) = *(const u16x8*)(Vb + (size_t)row * 2048 + kt * 64 + dc);
        }
        __syncthreads();

        // S^T = K.Q^T : 4 key-tiles (c) x 2 q-subtiles
        f32x4 st[2][4];
        for (int c = 0; c < 4; ++c) {
            const bf16x8 kf0 = *(const bf16x8*)(&Ks[(c * 16 + r) * 72 + q4 * 8]);
            const bf16x8 kf1 = *(const bf16x8*)(&Ks[(c * 16 + r) * 72 + 32 + q4 * 8]);
            for (int qs = 0; qs < 2; ++qs) {
                f32x4 z = (f32x4){0.f, 0.f, 0.f, 0.f};
                z = __builtin_amdgcn_mfma_f32_16x16x32_bf16(kf0, qf[qs][0], z, 0, 0, 0);
                z = __builtin_amdgcn_mfma_f32_16x16x32_bf16(kf1, qf[qs][1], z, 0, 0, 0);
                st[qs][c] = z;
            }
        }

        // online softmax in log2 domain (scores already scaled by 0.125*log2e)
        for (int qs = 0; qs < 2; ++qs) {
            float vmax = st[qs][0][0];
            for (int c = 0; c < 4; ++c)
                for (int g = 0; g < 4; ++g) vmax = fmaxf(vmax, st[qs][c][g]);
            vmax = fmaxf(vmax, __shfl_xor(vmax, 16));
            vmax = fmaxf(vmax, __shfl_xor(vmax, 32));
            const float mnew = fmaxf(m_i[qs], vmax);
            const float alpha = exp2f(m_i[qs] - mnew);
            float lsum = 0.f;
            const int pb = pbase0 + qs * 16 * 72 + r * 72;
            for (int c = 0; c < 4; ++c) {
                s16x4 pk;
                for (int g = 0; g < 4; ++g) {
                    const float p = exp2f(st[qs][c][g] - mnew);
                    lsum += p;
                    pk[g] = f2bf(p);
                }
                *(s16x4*)(&Ps[pb + c * 16 + q4 * 4]) = pk;
            }
            lsum += __shfl_xor(lsum, 16);
            lsum += __shfl_xor(lsum, 32);
            l_i[qs] = l_i[qs] * alpha + lsum;
            m_i[qs] = mnew;
            for (int nt = 0; nt < 4; ++nt)
                for (int g = 0; g < 4; ++g) o[qs][nt][g] *= alpha;
        }
        asm volatile("s_waitcnt lgkmcnt(0)" ::: "memory");  // P writes visible (wave-local)

        // O^T += V^T.P^T
        for (int ko = 0; ko < 2; ++ko) {
            bf16x8 pf[2];
            for (int qs = 0; qs < 2; ++qs)
                pf[qs] = *(const bf16x8*)(&Ps[pbase0 + qs * 16 * 72 + r * 72 + ko * 32 + q4 * 8]);
            for (int nt = 0; nt < 4; ++nt) {
                const bf16x8 vf = *(const bf16x8*)(&Vs[(nt * 16 + r) * 72 + ko * 32 + q4 * 8]);
                for (int qs = 0; qs < 2; ++qs)
                    o[qs][nt] = __builtin_amdgcn_mfma_f32_16x16x32_bf16(vf, pf[qs], o[qs][nt], 0, 0, 0);
            }
        }
        __syncthreads();
    }

    // epilogue: lane holds O^T[dval=nt*16+q4*4+g][query=r] -> packed b64 stores
    for (int qs = 0; qs < 2; ++qs) {
        const float inv = 1.0f / l_i[qs];
        const int srow = qt * 128 + w * 32 + qs * 16 + r;
        const size_t base = ((size_t)(b * 2048 + srow)) * 1024 + h * 64;
        for (int nt = 0; nt < 4; ++nt) {
            s16x4 pk;
            for (int g = 0; g < 4; ++g) pk[g] = f2bf(o[qs][nt][g] * inv);
            *(s16x4*)(Og + base + nt * 16 + q4 * 4) = pk;
        }
    }
}

// ---------------- output GEMM ----------------
// A = attn [8192][1024] bf16, Bt = woutT [1024][1024] bf16, out fp32 + bias.
__global__ __launch_bounds__(256, 2) void gemm_out_kernel(
        const short* __restrict__ A, const short* __restrict__ Bt,
        const float* __restrict__ bias, float* __restrict__ out) {
    __shared__ short As[128 * 64];
    __shared__ short Bs[128 * 64];
    const int t = threadIdx.x;
    const int w = t >> 6, lane = t & 63, r = lane & 15, q4 = lane >> 4;
    const int n0 = blockIdx.x * 128, m0 = blockIdx.y * 128;
    const int wm = (w & 1) * 64, wn = (w >> 1) * 64;

    f32x4 acc[4][4];
    for (int i = 0; i < 4; ++i)
        for (int j = 0; j < 4; ++j)
            acc[i][j] = (f32x4){0.f, 0.f, 0.f, 0.f};

    for (int kk = 0; kk < 1024; kk += 64) {
        for (int ii = 0; ii < 4; ++ii) {
            const int p = t + 256 * ii;
            const int row = p >> 3;
            const int gg = (p & 7) ^ (row & 7);
            gload_lds16(A + (size_t)(m0 + row) * 1024 + kk + gg * 8, &As[p * 8]);
            gload_lds16(Bt + (size_t)(n0 + row) * 1024 + kk + gg * 8, &Bs[p * 8]);
        }
        __syncthreads();
        for (int ko = 0; ko < 2; ++ko) {
            bf16x8 af[4], bfr[4];
            for (int i = 0; i < 4; ++i) {
                const int R = wm + i * 16 + r;
                af[i] = *(const bf16x8*)(&As[R * 64 + (((ko * 4 + q4) ^ (R & 7)) * 8)]);
            }
            for (int j = 0; j < 4; ++j) {
                const int R = wn + j * 16 + r;
                bfr[j] = *(const bf16x8*)(&Bs[R * 64 + (((ko * 4 + q4) ^ (R & 7)) * 8)]);
            }
            for (int i = 0; i < 4; ++i)
                for (int j = 0; j < 4; ++j)
                    acc[i][j] = __builtin_amdgcn_mfma_f32_16x16x32_bf16(af[i], bfr[j], acc[i][j], 0, 0, 0);
        }
        __syncthreads();
    }

    for (int i = 0; i < 4; ++i) {
        for (int j = 0; j < 4; ++j) {
            const int gn = n0 + wn + j * 16 + r;
            const float bv = bias[gn];
            for (int g = 0; g < 4; ++g) {
                const int gm = m0 + wm + i * 16 + q4 * 4 + g;
                out[(size_t)gm * 1024 + gn] = acc[i][j][g] + bv;
            }
        }
    }
}

// ---------------- launch ----------------

extern "C" void kernel_launch(void* const* d_in, const int* in_sizes, int n_in,
                              void* d_out, int out_size, void* d_ws, size_t ws_size,
                              hipStream_t stream) {
    const float* x     = (const float*)d_in[0];
    const float* w_qkv = (const float*)d_in[1];
    const float* b_qkv = (const float*)d_in[2];
    const float* w_out = (const float*)d_in[3];
    const float* b_out = (const float*)d_in[4];
    float* out = (float*)d_out;

    char* ws = (char*)d_ws;
    short* xb    = (short*)(ws);                     // 16 MB, reused as attn output
    short* wqkvT = (short*)(ws + 16777216);          // 6 MB
    short* woutT = (short*)(ws + 23068672);          // 2 MB
    short* Qg    = (short*)(ws + 25165824);          // 16 MB
    short* Kg    = (short*)(ws + 41943040);          // 16 MB
    short* Vtg   = (short*)(ws + 58720256);          // 16 MB  (total 72 MB)
    short* attn  = xb;                               // alias: xb consumed before attn written

    cvt_bf16_kernel<<<4096, 256, 0, stream>>>(x, xb);
    transpose_cvt_kernel<<<dim3(96, 32), 256, 0, stream>>>(w_qkv, wqkvT, 1024, 3072);
    transpose_cvt_kernel<<<dim3(32, 32), 256, 0, stream>>>(w_out, woutT, 1024, 1024);
    gemm_qkv_kernel<<<dim3(24, 64), 256, 0, stream>>>(xb, wqkvT, b_qkv, Qg, Kg, Vtg);
    attn_kernel<<<1024, 256, 0, stream>>>(Qg, Kg, Vtg, attn);
    gemm_out_kernel<<<dim3(8, 64), 256, 0, stream>>>(attn, woutT, b_out, out);
}

// Round 3
// 323.550 us; speedup vs baseline: 1.3377x; 1.2016x over previous
//
#include <hip/hip_runtime.h>
#include <hip/hip_bf16.h>

// B=4, S=2048, E=1024, H=16, D=64.
// Pipeline (bf16 MFMA, fp32 accum):
//   1. x fp32 -> xb bf16 [8192][1024]
//   2. w_qkv -> wqkvT bf16 [3072][1024]; w_out -> woutT bf16 [1024][1024]
//   3. QKV GEMM (global_load_lds, BK=64, XOR swizzle) -> Q [B,H,S,D] (pre-scaled
//      by 0.125*log2e), K [B,H,S,D], V^T [B,H,D,S]
//   4. flash attention, S^T-swapped, packed-cvt softmax, l-via-MFMA -> attn bf16
//   5. out GEMM (+bias) -> d_out fp32

typedef short bf16x8 __attribute__((ext_vector_type(8)));
typedef unsigned short u16x8 __attribute__((ext_vector_type(8)));
typedef short s16x4 __attribute__((ext_vector_type(4)));
typedef float f32x4 __attribute__((ext_vector_type(4)));

#define QSCALE 0.18033688011112042f   // 0.125 * log2(e)

__device__ inline short f2bf(float f) {
    unsigned int u = __builtin_bit_cast(unsigned int, f);
    u += 0x7fffu + ((u >> 16) & 1u);   // round-to-nearest-even
    return (short)(u >> 16);
}

// pack two fp32 -> two bf16 in one dword (a -> low, b -> high)
__device__ inline unsigned int pack2bf(float a, float b) {
#if __has_builtin(__builtin_amdgcn_cvt_pk_bf16_f32)
    typedef __bf16 bf2 __attribute__((ext_vector_type(2)));
    bf2 v = __builtin_amdgcn_cvt_pk_bf16_f32(a, b);
    return __builtin_bit_cast(unsigned int, v);
#else
    return (unsigned int)(unsigned short)f2bf(a) |
           ((unsigned int)(unsigned short)f2bf(b) << 16);
#endif
}

__device__ inline void gload_lds16(const short* g, short* l) {
    __builtin_amdgcn_global_load_lds(
        (const __attribute__((address_space(1))) unsigned int*)g,
        (__attribute__((address_space(3))) unsigned int*)l, 16, 0, 0);
}

// ---------------- conversion kernels ----------------

__global__ __launch_bounds__(256) void cvt_bf16_kernel(const float* __restrict__ in,
                                                       short* __restrict__ out) {
    int i = blockIdx.x * 256 + threadIdx.x;        // each thread: 8 elements
    const float4 a = *(const float4*)(in + (size_t)i * 8);
    const float4 b = *(const float4*)(in + (size_t)i * 8 + 4);
    unsigned int o0 = pack2bf(a.x, a.y), o1 = pack2bf(a.z, a.w);
    unsigned int o2 = pack2bf(b.x, b.y), o3 = pack2bf(b.z, b.w);
    uint4 o = {o0, o1, o2, o3};
    *(uint4*)(out + (size_t)i * 8) = o;
}

// in [K][N] fp32  ->  out [N][K] bf16
__global__ __launch_bounds__(256) void transpose_cvt_kernel(const float* __restrict__ in,
                                                            short* __restrict__ out,
                                                            int K, int N) {
    __shared__ float tile[32][33];
    int tx = threadIdx.x & 31, ty = threadIdx.x >> 5;   // ty 0..7
    int nt = blockIdx.x * 32, kt = blockIdx.y * 32;
    for (int i = 0; i < 4; ++i)
        tile[ty + i * 8][tx] = in[(size_t)(kt + ty + i * 8) * N + nt + tx];
    __syncthreads();
    for (int i = 0; i < 4; ++i)
        out[(size_t)(nt + ty + i * 8) * K + kt + tx] = f2bf(tile[tx][ty + i * 8]);
}

// ---------------- QKV GEMM ----------------
// A = xb [8192][1024] bf16, Bt = wqkvT [3072][1024] bf16.  Tile 128x128, BK=64.
__global__ __launch_bounds__(256, 2) void gemm_qkv_kernel(
        const short* __restrict__ A, const short* __restrict__ Bt,
        const float* __restrict__ bias,
        short* __restrict__ Qg, short* __restrict__ Kg, short* __restrict__ Vtg) {
    __shared__ short As[128 * 64];
    __shared__ short Bs[128 * 64];
    const int t = threadIdx.x;
    const int w = t >> 6, lane = t & 63, r = lane & 15, q4 = lane >> 4;
    const int n0 = blockIdx.x * 128, m0 = blockIdx.y * 128;
    const int wm = (w & 1) * 64, wn = (w >> 1) * 64;

    f32x4 acc[4][4];
    for (int i = 0; i < 4; ++i)
        for (int j = 0; j < 4; ++j)
            acc[i][j] = (f32x4){0.f, 0.f, 0.f, 0.f};

    for (int kk = 0; kk < 1024; kk += 64) {
        for (int ii = 0; ii < 4; ++ii) {
            const int p = t + 256 * ii;
            const int row = p >> 3;
            const int gg = (p & 7) ^ (row & 7);
            gload_lds16(A + (size_t)(m0 + row) * 1024 + kk + gg * 8, &As[p * 8]);
            gload_lds16(Bt + (size_t)(n0 + row) * 1024 + kk + gg * 8, &Bs[p * 8]);
        }
        __syncthreads();
        for (int ko = 0; ko < 2; ++ko) {
            bf16x8 af[4], bfr[4];
            for (int i = 0; i < 4; ++i) {
                const int R = wm + i * 16 + r;
                af[i] = *(const bf16x8*)(&As[R * 64 + (((ko * 4 + q4) ^ (R & 7)) * 8)]);
            }
            for (int j = 0; j < 4; ++j) {
                const int R = wn + j * 16 + r;
                bfr[j] = *(const bf16x8*)(&Bs[R * 64 + (((ko * 4 + q4) ^ (R & 7)) * 8)]);
            }
            for (int i = 0; i < 4; ++i)
                for (int j = 0; j < 4; ++j)
                    acc[i][j] = __builtin_amdgcn_mfma_f32_16x16x32_bf16(af[i], bfr[j], acc[i][j], 0, 0, 0);
        }
        __syncthreads();
    }

    // epilogue: scatter into Q (scaled by 0.125*log2e), K, V^T
    for (int i = 0; i < 4; ++i) {
        for (int j = 0; j < 4; ++j) {
            const int gn = n0 + wn + j * 16 + r;
            const int h = gn / 192;
            const int rr = gn - h * 192;
            const float bv = bias[gn];
            for (int g = 0; g < 4; ++g) {
                const int gm = m0 + wm + i * 16 + q4 * 4 + g;
                const int bb = gm >> 11;          // batch
                const int s2 = gm & 2047;         // seq
                float v = acc[i][j][g] + bv;
                const size_t bh = (size_t)(bb * 16 + h);
                if (rr < 64) {
                    Qg[(bh * 2048 + s2) * 64 + rr] = f2bf(v * QSCALE);
                } else if (rr < 128) {
                    Kg[(bh * 2048 + s2) * 64 + (rr - 64)] = f2bf(v);
                } else {
                    Vtg[(bh * 64 + (rr - 128)) * 2048 + s2] = f2bf(v);
                }
            }
        }
    }
}

// ---------------- flash attention (S^T-swapped, lean softmax) ----------------
// Q,K: [B,H,S,D] bf16 (Q pre-scaled by 0.125*log2e), Vt: [B,H,D,S] bf16.
// Out: attn [B,S,H*D] bf16.
// Block: 256 thr = 4 waves; Bq=128 (2 q-subtiles/wave); Bk=64; 32 kv iters.
// S^T = K.Q^T ; O^T = V^T.P^T ; l = ones.P^T (MFMA, pre-reduced per lane).
// K/V tiles staged via global_load_lds, XOR-granule swizzle, stride 64 (no pad):
//   LDS granule slot (row, gs) holds global granule gs ^ (row&7); granule = 8 shorts.
__global__ __launch_bounds__(256, 3) void attn_kernel(
        const short* __restrict__ Qg, const short* __restrict__ Kg,
        const short* __restrict__ Vtg, short* __restrict__ Og) {
    __shared__ short Ks[64 * 64];
    __shared__ short Vs[64 * 64];
    __shared__ short Ps[128 * 72];    // per wave: 2 q-subtiles x 16 rows x 72
    const int t = threadIdx.x;
    const int w = t >> 6, lane = t & 63, r = lane & 15, q4 = lane >> 4;
    const int blk = blockIdx.x;
    const int qt = blk & 15;
    const int h = (blk >> 4) & 15;
    const int b = blk >> 8;
    const size_t bh = (size_t)b * 16 + h;
    const short* Qb = Qg + bh * 2048 * 64;
    const short* Kb = Kg + bh * 2048 * 64;
    const short* Vb = Vtg + bh * 64 * 2048;

    // staging offsets (loop-invariant): thread handles granules t and t+256
    const int r1 = t >> 3, g1 = (t & 7) ^ (r1 & 7);
    const int r2 = 32 + (t >> 3), g2 = (t & 7) ^ (r2 & 7);
    const short* kptr1 = Kb + r1 * 64 + g1 * 8;
    const short* kptr2 = Kb + r2 * 64 + g2 * 8;
    const short* vptr1 = Vb + (size_t)r1 * 2048 + g1 * 8;
    const short* vptr2 = Vb + (size_t)r2 * 2048 + g2 * 8;
    short* klds1 = &Ks[t * 8];
    short* klds2 = &Ks[(256 + t) * 8];
    short* vlds1 = &Vs[t * 8];
    short* vlds2 = &Vs[(256 + t) * 8];

    // swizzled fragment granule offsets (loop-invariant)
    const int ga = (q4 ^ (r & 7)) * 8;          // granules 0..3 ^ swz
    const int gb = ((4 + q4) ^ (r & 7)) * 8;    // granules 4..7 ^ swz

    // Q fragments (B-operand): lane holds Q[qrow][d = half*32 + q4*8 ..]
    bf16x8 qf[2][2];
    for (int qs = 0; qs < 2; ++qs) {
        const int qrow = qt * 128 + w * 32 + qs * 16 + r;
        qf[qs][0] = *(const bf16x8*)(Qb + (size_t)qrow * 64 + q4 * 8);
        qf[qs][1] = *(const bf16x8*)(Qb + (size_t)qrow * 64 + 32 + q4 * 8);
    }

    bf16x8 onesf;
    for (int i = 0; i < 8; ++i) onesf[i] = (short)0x3F80;   // bf16 1.0

    f32x4 o[2][4], ol[2];
    for (int qs = 0; qs < 2; ++qs) {
        ol[qs] = (f32x4){0.f, 0.f, 0.f, 0.f};
        for (int nt = 0; nt < 4; ++nt) o[qs][nt] = (f32x4){0.f, 0.f, 0.f, 0.f};
    }
    float m_i[2] = {-INFINITY, -INFINITY};

    const int pbase0 = (w * 32) * 72;

    for (int kt = 0; kt < 32; ++kt) {
        gload_lds16(kptr1 + kt * 4096, klds1);
        gload_lds16(kptr2 + kt * 4096, klds2);
        gload_lds16(vptr1 + kt * 64, vlds1);
        gload_lds16(vptr2 + kt * 64, vlds2);
        __syncthreads();

        // S^T = K.Q^T : 4 key-tiles (c) x 2 q-subtiles
        f32x4 st[2][4];
        for (int c = 0; c < 4; ++c) {
            const int R = (c * 16 + r) * 64;
            const bf16x8 kf0 = *(const bf16x8*)(&Ks[R + ga]);
            const bf16x8 kf1 = *(const bf16x8*)(&Ks[R + gb]);
            for (int qs = 0; qs < 2; ++qs) {
                f32x4 z = (f32x4){0.f, 0.f, 0.f, 0.f};
                z = __builtin_amdgcn_mfma_f32_16x16x32_bf16(kf0, qf[qs][0], z, 0, 0, 0);
                z = __builtin_amdgcn_mfma_f32_16x16x32_bf16(kf1, qf[qs][1], z, 0, 0, 0);
                st[qs][c] = z;
            }
        }

        // online softmax in log2 domain
        for (int qs = 0; qs < 2; ++qs) {
            f32x4 vm4 = st[qs][0];
            for (int g = 0; g < 4; ++g) vm4[g] = fmaxf(fmaxf(st[qs][0][g], st[qs][1][g]),
                                                       fmaxf(st[qs][2][g], st[qs][3][g]));
            float vmax = fmaxf(fmaxf(vm4[0], vm4[1]), fmaxf(vm4[2], vm4[3]));
            vmax = fmaxf(vmax, __shfl_xor(vmax, 16));
            vmax = fmaxf(vmax, __shfl_xor(vmax, 32));
            const float mnew = fmaxf(m_i[qs], vmax);
            const float alpha = exp2f(m_i[qs] - mnew);
            m_i[qs] = mnew;
            const int pb = pbase0 + qs * 16 * 72 + r * 72 + q4 * 4;
            for (int c = 0; c < 4; ++c) {
                const float p0 = exp2f(st[qs][c][0] - mnew);
                const float p1 = exp2f(st[qs][c][1] - mnew);
                const float p2 = exp2f(st[qs][c][2] - mnew);
                const float p3 = exp2f(st[qs][c][3] - mnew);
                uint2 pk = {pack2bf(p0, p1), pack2bf(p2, p3)};
                *(uint2*)(&Ps[pb + c * 16]) = pk;
            }
            for (int nt = 0; nt < 4; ++nt)
                for (int g = 0; g < 4; ++g) o[qs][nt][g] *= alpha;
            for (int g = 0; g < 4; ++g) ol[qs][g] *= alpha;
        }
        asm volatile("s_waitcnt lgkmcnt(0)" ::: "memory");  // P writes visible (wave-local)

        // O^T += V^T.P^T ; l += ones.P^T
        for (int ko = 0; ko < 2; ++ko) {
            const int gk = (ko == 0) ? ga : gb;
            bf16x8 pf[2];
            for (int qs = 0; qs < 2; ++qs)
                pf[qs] = *(const bf16x8*)(&Ps[pbase0 + qs * 16 * 72 + r * 72 + ko * 32 + q4 * 8]);
            for (int qs = 0; qs < 2; ++qs)
                ol[qs] = __builtin_amdgcn_mfma_f32_16x16x32_bf16(onesf, pf[qs], ol[qs], 0, 0, 0);
            for (int nt = 0; nt < 4; ++nt) {
                const bf16x8 vf = *(const bf16x8*)(&Vs[(nt * 16 + r) * 64 + gk]);
                for (int qs = 0; qs < 2; ++qs)
                    o[qs][nt] = __builtin_amdgcn_mfma_f32_16x16x32_bf16(vf, pf[qs], o[qs][nt], 0, 0, 0);
            }
        }
        __syncthreads();
    }

    // epilogue: lane holds O^T[dval=nt*16+q4*4+g][query=r] -> packed b64 stores
    for (int qs = 0; qs < 2; ++qs) {
        const float inv = 1.0f / ol[qs][0];
        const int srow = qt * 128 + w * 32 + qs * 16 + r;
        const size_t base = ((size_t)(b * 2048 + srow)) * 1024 + h * 64;
        for (int nt = 0; nt < 4; ++nt) {
            uint2 pk = {pack2bf(o[qs][nt][0] * inv, o[qs][nt][1] * inv),
                        pack2bf(o[qs][nt][2] * inv, o[qs][nt][3] * inv)};
            *(uint2*)(Og + base + nt * 16 + q4 * 4) = pk;
        }
    }
}

// ---------------- output GEMM ----------------
// A = attn [8192][1024] bf16, Bt = woutT [1024][1024] bf16, out fp32 + bias.
__global__ __launch_bounds__(256, 2) void gemm_out_kernel(
        const short* __restrict__ A, const short* __restrict__ Bt,
        const float* __restrict__ bias, float* __restrict__ out) {
    __shared__ short As[128 * 64];
    __shared__ short Bs[128 * 64];
    const int t = threadIdx.x;
    const int w = t >> 6, lane = t & 63, r = lane & 15, q4 = lane >> 4;
    const int n0 = blockIdx.x * 128, m0 = blockIdx.y * 128;
    const int wm = (w & 1) * 64, wn = (w >> 1) * 64;

    f32x4 acc[4][4];
    for (int i = 0; i < 4; ++i)
        for (int j = 0; j < 4; ++j)
            acc[i][j] = (f32x4){0.f, 0.f, 0.f, 0.f};

    for (int kk = 0; kk < 1024; kk += 64) {
        for (int ii = 0; ii < 4; ++ii) {
            const int p = t + 256 * ii;
            const int row = p >> 3;
            const int gg = (p & 7) ^ (row & 7);
            gload_lds16(A + (size_t)(m0 + row) * 1024 + kk + gg * 8, &As[p * 8]);
            gload_lds16(Bt + (size_t)(n0 + row) * 1024 + kk + gg * 8, &Bs[p * 8]);
        }
        __syncthreads();
        for (int ko = 0; ko < 2; ++ko) {
            bf16x8 af[4], bfr[4];
            for (int i = 0; i < 4; ++i) {
                const int R = wm + i * 16 + r;
                af[i] = *(const bf16x8*)(&As[R * 64 + (((ko * 4 + q4) ^ (R & 7)) * 8)]);
            }
            for (int j = 0; j < 4; ++j) {
                const int R = wn + j * 16 + r;
                bfr[j] = *(const bf16x8*)(&Bs[R * 64 + (((ko * 4 + q4) ^ (R & 7)) * 8)]);
            }
            for (int i = 0; i < 4; ++i)
                for (int j = 0; j < 4; ++j)
                    acc[i][j] = __builtin_amdgcn_mfma_f32_16x16x32_bf16(af[i], bfr[j], acc[i][j], 0, 0, 0);
        }
        __syncthreads();
    }

    for (int i = 0; i < 4; ++i) {
        for (int j = 0; j < 4; ++j) {
            const int gn = n0 + wn + j * 16 + r;
            const float bv = bias[gn];
            for (int g = 0; g < 4; ++g) {
                const int gm = m0 + wm + i * 16 + q4 * 4 + g;
                out[(size_t)gm * 1024 + gn] = acc[i][j][g] + bv;
            }
        }
    }
}

// ---------------- launch ----------------

extern "C" void kernel_launch(void* const* d_in, const int* in_sizes, int n_in,
                              void* d_out, int out_size, void* d_ws, size_t ws_size,
                              hipStream_t stream) {
    const float* x     = (const float*)d_in[0];
    const float* w_qkv = (const float*)d_in[1];
    const float* b_qkv = (const float*)d_in[2];
    const float* w_out = (const float*)d_in[3];
    const float* b_out = (const float*)d_in[4];
    float* out = (float*)d_out;

    char* ws = (char*)d_ws;
    short* xb    = (short*)(ws);                     // 16 MB, reused as attn output
    short* wqkvT = (short*)(ws + 16777216);          // 6 MB
    short* woutT = (short*)(ws + 23068672);          // 2 MB
    short* Qg    = (short*)(ws + 25165824);          // 16 MB
    short* Kg    = (short*)(ws + 41943040);          // 16 MB
    short* Vtg   = (short*)(ws + 58720256);          // 16 MB  (total 72 MB)
    short* attn  = xb;                               // alias: xb consumed before attn written

    cvt_bf16_kernel<<<4096, 256, 0, stream>>>(x, xb);
    transpose_cvt_kernel<<<dim3(96, 32), 256, 0, stream>>>(w_qkv, wqkvT, 1024, 3072);
    transpose_cvt_kernel<<<dim3(32, 32), 256, 0, stream>>>(w_out, woutT, 1024, 1024);
    gemm_qkv_kernel<<<dim3(24, 64), 256, 0, stream>>>(xb, wqkvT, b_qkv, Qg, Kg, Vtg);
    attn_kernel<<<1024, 256, 0, stream>>>(Qg, Kg, Vtg, attn);
    gemm_out_kernel<<<dim3(8, 64), 256, 0, stream>>>(attn, woutT, b_out, out);
}